// Round 1
// baseline (725.991 us; speedup 1.0000x reference)
//
#include <hip/hip_runtime.h>

#define B_ 32
#define T_ 24
#define N_ 512
#define F_ 64
#define H_ 256

typedef float f32x4 __attribute__((ext_vector_type(4)));
typedef unsigned short u16;
typedef u16 u16x4 __attribute__((ext_vector_type(4)));
typedef u16 u16x8 __attribute__((ext_vector_type(8)));
typedef __bf16 bf16x8 __attribute__((ext_vector_type(8)));

static __device__ __forceinline__ u16 f2bf(float f) {
    return __builtin_bit_cast(u16, (__bf16)f);
}
static __device__ __forceinline__ unsigned int pack2bf(float lo, float hi) {
    return (unsigned int)f2bf(lo) | ((unsigned int)f2bf(hi) << 16);
}

// tmp1[f][k] = sum_h w1[h,f,1] * gc_w[h,k]   (64 x 256 fp32)
__global__ void k_tmp1(const float* __restrict__ w1, const float* __restrict__ gcw,
                       float* __restrict__ tmp1) {
    int f = blockIdx.x, k = threadIdx.x;
    float acc = 0.f;
    for (int h = 0; h < H_; ++h)
        acc += w1[(h * F_ + f) * 3 + 1] * gcw[h * H_ + k];
    tmp1[f * H_ + k] = acc;
}

// WT[h][f] = bf16( sum_k tmp1[f][k] * w2[h,k,1] )   (256 x 64 bf16, row-major h)
__global__ void k_WT(const float* __restrict__ tmp1, const float* __restrict__ w2,
                     u16* __restrict__ WT) {
    int h = blockIdx.x, f = threadIdx.x;
    float acc = 0.f;
    for (int k = 0; k < H_; ++k)
        acc += tmp1[f * H_ + k] * w2[(h * H_ + k) * 3 + 1];
    WT[h * F_ + f] = f2bf(acc);
}

// Folded epilogue vectors: scale[h], bias[h], c2s[h]
__global__ void k_vec(const float* __restrict__ b1, const float* __restrict__ gcw,
                      const float* __restrict__ gcb, const float* __restrict__ w2,
                      const float* __restrict__ b2, const float* __restrict__ gamma,
                      const float* __restrict__ beta, const float* __restrict__ rm,
                      const float* __restrict__ rv,
                      float* __restrict__ scale, float* __restrict__ bias,
                      float* __restrict__ c2s) {
    __shared__ float e[H_];
    int t = threadIdx.x;
    float a = 0.f;
    for (int h = 0; h < H_; ++h) a += b1[h] * gcw[h * H_ + t];
    e[t] = a;
    __syncthreads();
    float c2 = 0.f, d = 0.f;
    for (int k = 0; k < H_; ++k) {
        float w = w2[(t * H_ + k) * 3 + 1];
        c2 += e[k] * w;
        d  += gcb[k] * w;
    }
    d += b2[t];
    float inv = gamma[t] * rsqrtf(rv[t] + 1e-5f);
    scale[t] = inv;
    bias[t]  = d * inv + beta[t] - rm[t] * inv;
    c2s[t]   = c2 * inv;
}

// rs[b*512+n] = sum_m adj[b][n][m]
__global__ void k_rs(const float* __restrict__ adj, float* __restrict__ rs) {
    int w = threadIdx.x >> 6, l = threadIdx.x & 63;
    int row = blockIdx.x * 4 + w;
    const float* p = adj + (size_t)row * N_;
    float v = 0.f;
    #pragma unroll
    for (int i = 0; i < 8; ++i) v += p[l + i * 64];
    #pragma unroll
    for (int off = 32; off; off >>= 1) v += __shfl_xor(v, off, 64);
    if (l == 0) rs[row] = v;
}

// adj fp32 -> bf16 (same layout)
__global__ void k_adjc(const float* __restrict__ adj, u16* __restrict__ adjbf) {
    size_t base = ((size_t)blockIdx.x * 256 + threadIdx.x) * 8;
    f32x4 v0 = *(const f32x4*)(adj + base);
    f32x4 v1 = *(const f32x4*)(adj + base + 4);
    u16x8 o;
    o[0] = f2bf(v0[0]); o[1] = f2bf(v0[1]); o[2] = f2bf(v0[2]); o[3] = f2bf(v0[3]);
    o[4] = f2bf(v1[0]); o[5] = f2bf(v1[1]); o[6] = f2bf(v1[2]); o[7] = f2bf(v1[3]);
    *(u16x8*)(adjbf + base) = o;
}

// Main fused kernel: per block = one (b,t) and 64 output rows.
// Phase 1: Y(64x64) = adj_tile(64x512) @ x[b,t](512x64)   (MFMA bf16, BK=64)
// Phase 2: out(64x256) = Y @ W(64x256) * scale + rs*c2s + bias, ReLU
__global__ __launch_bounds__(256) void k_main(
    const float* __restrict__ x, const u16* __restrict__ adjbf,
    const u16* __restrict__ WT, const float* __restrict__ scale,
    const float* __restrict__ bias, const float* __restrict__ c2s,
    const float* __restrict__ rs, float* __restrict__ out)
{
    __shared__ u16 sA[64 * 72];  // adj tile [m][k], stride 72 (16B-aligned rows)
    __shared__ u16 sX[64 * 68];  // x^T tile [f][k],  stride 68 (k-pair packed writes)
    __shared__ u16 sY[64 * 68];  // Y tile   [m][f],  stride 68

    const int tid = threadIdx.x;
    const int w  = tid >> 6;          // wave 0..3
    const int l  = tid & 63;
    const int lg = l >> 4;            // lane group 0..3
    const int lr = l & 15;            // lane row/col 0..15

    const int bid   = blockIdx.x;
    const int bt    = bid >> 3;
    const int mtile = bid & 7;
    const int b     = bt / T_;

    const u16*  adjBase = adjbf + ((size_t)b * N_ + mtile * 64) * N_;
    const float* xBase  = x + (size_t)bt * N_ * F_;

    f32x4 acc1[4];
    #pragma unroll
    for (int i = 0; i < 4; ++i)
        #pragma unroll
        for (int j = 0; j < 4; ++j) acc1[i][j] = 0.f;

    for (int s = 0; s < 8; ++s) {
        const int k0 = s * 64;
        // stage sA: 64 rows x 64 bf16 (straight copy)
        #pragma unroll
        for (int it = 0; it < 2; ++it) {
            int i = tid + it * 256;                 // 0..511
            int row = i >> 3, c8 = (i & 7) * 8;
            u16x8 v = *(const u16x8*)(adjBase + (size_t)row * N_ + k0 + c8);
            *(u16x8*)(&sA[row * 72 + c8]) = v;
        }
        // stage sX: transpose x tile (k-pairs packed into u32 words)
        #pragma unroll
        for (int it = 0; it < 2; ++it) {
            int i = tid + it * 256;                 // 0..511
            int kp = i >> 4, f4 = (i & 15) * 4;     // kp 0..31, f4 0..60
            const float* px = xBase + (size_t)(k0 + 2 * kp) * F_ + f4;
            f32x4 v0 = *(const f32x4*)px;
            f32x4 v1 = *(const f32x4*)(px + F_);
            #pragma unroll
            for (int ii = 0; ii < 4; ++ii)
                ((unsigned int*)sX)[(f4 + ii) * 34 + kp] = pack2bf(v0[ii], v1[ii]);
        }
        __syncthreads();

        #pragma unroll
        for (int kc = 0; kc < 2; ++kc) {
            u16x8 av = *(const u16x8*)(&sA[(w * 16 + lr) * 72 + kc * 32 + lg * 8]);
            bf16x8 af = __builtin_bit_cast(bf16x8, av);
            #pragma unroll
            for (int nf = 0; nf < 4; ++nf) {
                const u16* pb = &sX[(nf * 16 + lr) * 68 + kc * 32 + lg * 8];
                u16x4 b0 = *(const u16x4*)pb;
                u16x4 b1v = *(const u16x4*)(pb + 4);
                u16x8 bb;
                #pragma unroll
                for (int j = 0; j < 4; ++j) { bb[j] = b0[j]; bb[j + 4] = b1v[j]; }
                acc1[nf] = __builtin_amdgcn_mfma_f32_16x16x32_bf16(
                    af, __builtin_bit_cast(bf16x8, bb), acc1[nf], 0, 0, 0);
            }
        }
        __syncthreads();
    }

    // write Y strip to LDS (each wave's own 16 rows; no cross-wave sharing)
    #pragma unroll
    for (int nf = 0; nf < 4; ++nf)
        #pragma unroll
        for (int r = 0; r < 4; ++r)
            sY[(w * 16 + lg * 4 + r) * 68 + nf * 16 + lr] = f2bf(acc1[nf][r]);

    f32x4 acc2[16];
    #pragma unroll
    for (int i = 0; i < 16; ++i)
        #pragma unroll
        for (int j = 0; j < 4; ++j) acc2[i][j] = 0.f;

    #pragma unroll
    for (int kc = 0; kc < 2; ++kc) {
        const u16* pa = &sY[(w * 16 + lr) * 68 + kc * 32 + lg * 8];
        u16x4 a0 = *(const u16x4*)pa;
        u16x4 a1 = *(const u16x4*)(pa + 4);
        u16x8 aa;
        #pragma unroll
        for (int j = 0; j < 4; ++j) { aa[j] = a0[j]; aa[j + 4] = a1[j]; }
        bf16x8 a2 = __builtin_bit_cast(bf16x8, aa);
        #pragma unroll
        for (int hf = 0; hf < 16; ++hf) {
            const u16* pw = WT + (hf * 16 + lr) * F_ + kc * 32 + lg * 8;
            bf16x8 bw = __builtin_bit_cast(bf16x8, *(const u16x8*)pw);
            acc2[hf] = __builtin_amdgcn_mfma_f32_16x16x32_bf16(a2, bw, acc2[hf], 0, 0, 0);
        }
    }

    // epilogue: scale/bias/rowsum*c2 + ReLU, fp32 stores
    const int grow0 = mtile * 64 + w * 16;
    float rsv[4];
    #pragma unroll
    for (int r = 0; r < 4; ++r) rsv[r] = rs[b * N_ + grow0 + lg * 4 + r];
    float* outBase = out + (size_t)bt * N_ * H_;
    #pragma unroll
    for (int hf = 0; hf < 16; ++hf) {
        int h = hf * 16 + lr;
        float sc = scale[h], bi = bias[h], cc = c2s[h];
        #pragma unroll
        for (int r = 0; r < 4; ++r) {
            int g = grow0 + lg * 4 + r;
            float v = acc2[hf][r] * sc + rsv[r] * cc + bi;
            outBase[(size_t)g * H_ + h] = v > 0.f ? v : 0.f;
        }
    }
}

extern "C" void kernel_launch(void* const* d_in, const int* in_sizes, int n_in,
                              void* d_out, int out_size, void* d_ws, size_t ws_size,
                              hipStream_t stream) {
    const float* x     = (const float*)d_in[0];
    const float* adj   = (const float*)d_in[1];
    const float* w1    = (const float*)d_in[2];
    const float* b1    = (const float*)d_in[3];
    const float* gcw   = (const float*)d_in[4];
    const float* gcb   = (const float*)d_in[5];
    const float* w2    = (const float*)d_in[6];
    const float* b2    = (const float*)d_in[7];
    const float* gamma = (const float*)d_in[8];
    const float* beta  = (const float*)d_in[9];
    const float* rm    = (const float*)d_in[10];
    const float* rv    = (const float*)d_in[11];
    float* out = (float*)d_out;

    char* ws = (char*)d_ws;
    float* tmp1  = (float*)(ws);                 // 65536 B
    u16*   WT    = (u16*)  (ws + 65536);         // 32768 B
    float* scale = (float*)(ws + 98304);         // 1024 B
    float* bias  = (float*)(ws + 99328);         // 1024 B
    float* c2s   = (float*)(ws + 100352);        // 1024 B
    float* rs    = (float*)(ws + 101376);        // 65536 B
    u16*   adjbf = (u16*)  (ws + 166912);        // 16777216 B

    k_tmp1<<<dim3(64),   dim3(256), 0, stream>>>(w1, gcw, tmp1);
    k_WT  <<<dim3(256),  dim3(64),  0, stream>>>(tmp1, w2, WT);
    k_vec <<<dim3(1),    dim3(256), 0, stream>>>(b1, gcw, gcb, w2, b2, gamma, beta, rm, rv,
                                                 scale, bias, c2s);
    k_rs  <<<dim3(4096), dim3(256), 0, stream>>>(adj, rs);
    k_adjc<<<dim3(4096), dim3(256), 0, stream>>>(adj, adjbf);
    k_main<<<dim3(6144), dim3(256), 0, stream>>>(x, adjbf, WT, scale, bias, c2s, rs, out);
}